// Round 12
// baseline (13068.596 us; speedup 1.0000x reference)
//
#include <hip/hip_runtime.h>
#include <hip/hip_bf16.h>

// Stacked 2-layer Elman RNN, B=2048 T=256 H=512 OUT=1.
//
// Round-11 lesson: LDS-staged B (global_load_lds + ds_read) lets the
// compiler's waitcnt pass see an LDS dependency it can't disambiguate, so it
// drains the DMA queue (vmcnt(0)-equivalent) before every consume — counted
// vmcnt(4/8) never took effect (depth-1 and depth-2 ran at identical
// ~2500cy/group). This round B-fragments NEVER touch LDS: inline-asm
// global_load_dwordx4 -> named VGPR ring (4 slots, constant indices under
// full unroll), prefetch distance 3, s_waitcnt vmcnt(12) + sched_barrier(0)
// (rule #18) as the ONLY in-loop waits. The asm loads are invisible to the
// compiler's ledger, so it cannot insert spurious drains.
//   - per-block kc-stagger (koff) kept: decorrelates the 16 blocks/XCD
//   - h0 double-buffered -> 2 barriers/step (B0, B2)
//   - x / biases / Wx0 preloaded before the loop; clean vmcnt(0) ledger
// Floor: 1.5MB/step/CU from L2; MFMA 0.4us/step/wave.

typedef _Float16 half8 __attribute__((ext_vector_type(8)));
typedef float f32x4 __attribute__((ext_vector_type(4)));

#define T_STEPS 256
#define H_DIM   512
#define BM      16

#define BARRIER() do { \
    asm volatile("s_waitcnt lgkmcnt(0)" ::: "memory"); \
    __builtin_amdgcn_s_barrier(); \
    asm volatile("" ::: "memory"); \
  } while (0)

// B-fragment load: global -> VGPR quad, bypassing the compiler's vmcnt ledger
__device__ __forceinline__ half8 gld16(const half8* p){
  half8 r;
  asm volatile("global_load_dwordx4 %0, %1, off" : "=v"(r) : "v"(p));
  return r;
}

__device__ __forceinline__ float tanh_fast(float z){
  float az = fabsf(z);
  float e  = __expf(-2.0f * az);
  float r  = (1.0f - e) * __builtin_amdgcn_rcpf(1.0f + e);
  return copysignf(r, z);
}

// fp32 [k][n] -> fp16 MFMA-B fragments: out[(nt*16+kc)*64+lane] = 8 halves,
// col = nt*16 + (lane&15), k = kc*32 + (lane>>4)*8 + j
__global__ void prep_w_45028437131357(const float* __restrict__ W,
                                      half8* __restrict__ out){
  int tid  = blockIdx.x * 256 + threadIdx.x;
  int lane = tid & 63;
  int kc   = (tid >> 6) & 15;
  int nt   = tid >> 10;
  int col  = nt * 16 + (lane & 15);
  int k0   = kc * 32 + (lane >> 4) * 8;
  half8 v;
#pragma unroll
  for (int j = 0; j < 8; ++j) v[j] = (_Float16)W[(k0 + j) * H_DIM + col];
  out[tid] = v;
}

// LDS h layout: element (row, c) at byte  row*1024 + ((c*2) ^ ((row&7)<<4))

__global__ __launch_bounds__(512, 2)
void rnn_main_45028437131357(const float* __restrict__ x,
                             const float* __restrict__ Wx0,
                             const float* __restrict__ bx0,
                             const float* __restrict__ bh0,
                             const float* __restrict__ bx1,
                             const float* __restrict__ bh1,
                             const float* __restrict__ Wfc,
                             const float* __restrict__ bfc,
                             const half8* __restrict__ Wh0f,
                             const half8* __restrict__ Wx1f,
                             const half8* __restrict__ Wh1f,
                             float* __restrict__ out){
  __shared__ __align__(16) char  h0d[2][BM * 1024];    // 32 KB (double buf)
  __shared__ __align__(16) char  h1s[BM * 1024];       // 16 KB
  __shared__ __align__(16) float xall[BM * 256];       // 16 KB, swizzled
  __shared__ char lds_pad[20 * 1024];                  // force 1 block/CU

  const int tid  = threadIdx.x;
  const int lane = tid & 63;
  const int w    = tid >> 6;            // 0..7, owns n-tiles 4w..4w+3
  const int w4   = 4 * w;
  const int r0   = blockIdx.x * BM;
  const int koff = (blockIdx.x >> 3) & 15;   // kc-stagger within each XCD

  if (out == nullptr) ((volatile char*)lds_pad)[0] = 1;  // keep pad alive

  // zero initial hidden state + preload x block into LDS
  for (int i = tid; i < BM * 256; i += 512){
    ((float*)h0d[0])[i] = 0.0f;
    ((float*)h1s)[i] = 0.0f;
    int r = i >> 8, c = i & 255;
    xall[r * 256 + (c ^ ((r & 7) << 2))] = x[(r0 + r) * T_STEPS + c];
  }

  const int cl      = lane & 15;
  const int kg      = lane >> 4;
  const int aBase   = cl * 1024 + kg * 16;   // + keff*64, then ^aSwz
  const int aSwz    = (cl & 7) << 4;
  const int rowBase = kg * 4;

  // per-column constants for the 4 owned n-tiles
  float wx0c[4], b0c[4], b1c[4];
  int   colA[4];
#pragma unroll
  for (int i = 0; i < 4; ++i){
    int col = (w4 + i) * 16 + cl;
    colA[i] = col;
    wx0c[i] = Wx0[col];
    b0c[i]  = bx0[col] + bh0[col];
    b1c[i]  = bx1[col] + bh1[col];
  }

  // register ring: 4 slots x 4 fragments (indices constant after unroll)
  half8 rb[4][4];

  // STAGE(G): issue 4 asm loads for group G. group -> matrix: 0-15 Wh0,
  // 16-31 Wh1, 32-47 Wx1; wraps at 48. kc-slot staggered by koff.
#define STAGE(G)                                                              \
  {                                                                           \
    int g48 = ((G) >= 48) ? (G) - 48 : (G);                                   \
    const half8* M = (g48 < 16) ? Wh0f : ((g48 < 32) ? Wh1f : Wx1f);          \
    int keff = ((g48 & 15) + koff) & 15;                                      \
    const half8* base = M + keff * 64 + lane;                                 \
    rb[(G) & 3][0] = gld16(base + (w4 + 0) * 1024);                           \
    rb[(G) & 3][1] = gld16(base + (w4 + 1) * 1024);                           \
    rb[(G) & 3][2] = gld16(base + (w4 + 2) * 1024);                           \
    rb[(G) & 3][3] = gld16(base + (w4 + 3) * 1024);                           \
  }

  // CONSUME(APTR, ACC, KC, G): A ds_read issued BEFORE the counted wait so
  // its LDS latency hides under the vmcnt stall; sched_barrier pins MFMAs
  // below the wait (rule #18).
#define CONSUME(APTR, ACC, KC, G)                                             \
  {                                                                           \
    int keff = (((KC) + koff) & 15);                                          \
    half8 a = *(const half8*)((APTR) + ((aBase + keff * 64) ^ aSwz));         \
    asm volatile("s_waitcnt vmcnt(12)");                                      \
    __builtin_amdgcn_sched_barrier(0);                                        \
    ACC[0] = __builtin_amdgcn_mfma_f32_16x16x32_f16(a, rb[(G)&3][0], ACC[0], 0,0,0); \
    ACC[1] = __builtin_amdgcn_mfma_f32_16x16x32_f16(a, rb[(G)&3][1], ACC[1], 0,0,0); \
    ACC[2] = __builtin_amdgcn_mfma_f32_16x16x32_f16(a, rb[(G)&3][2], ACC[2], 0,0,0); \
    ACC[3] = __builtin_amdgcn_mfma_f32_16x16x32_f16(a, rb[(G)&3][3], ACC[3], 0,0,0); \
  }

  // clean the vmcnt ledger (drain all compiler-tracked preloads), then
  // prime the ring with groups 0,1,2 (prefetch distance 3)
  asm volatile("s_waitcnt vmcnt(0)" ::: "memory");
  STAGE(0); STAGE(1); STAGE(2);

  const f32x4 z4 = {0.f, 0.f, 0.f, 0.f};
  int s = 0;

  for (int t = 0; t < T_STEPS; ++t){
    BARRIER();                            // B0: h1_new(t-1), h0d, xall visible

    const char* h0cur = h0d[s];
    char*       h0nxt = h0d[s ^ 1];

    f32x4 acc0[4] = {z4, z4, z4, z4};
    f32x4 acc1[4] = {z4, z4, z4, z4};

    // ---- A0: acc0 += h0_old @ Wh0 (groups 0..15) ----
#pragma unroll
    for (int kc = 0; kc < 16; ++kc){
      STAGE(kc + 3);
      CONSUME(h0cur, acc0, kc, kc);
    }
    // ---- A1: acc1 += h1_old @ Wh1 (groups 16..31) ----
#pragma unroll
    for (int kc = 0; kc < 16; ++kc){
      STAGE(kc + 19);
      CONSUME(h1s, acc1, kc, kc + 16);
    }

    // epilogue0: nh0 = tanh(acc0 + b0 + x*wx0) -> h0d[s^1] (own buffer; the
    // only prior readers of h0d[s^1] were last step's A0, sealed by B0)
    {
      float xv[4];
#pragma unroll
      for (int rg = 0; rg < 4; ++rg){
        int row = rowBase + rg;
        xv[rg] = xall[row * 256 + (t ^ ((row & 7) << 2))];
      }
#pragma unroll
      for (int i = 0; i < 4; ++i)
#pragma unroll
        for (int rg = 0; rg < 4; ++rg){
          float z = acc0[i][rg] + b0c[i] + xv[rg] * wx0c[i];
          int row = rowBase + rg;
          *(_Float16*)(h0nxt + row * 1024 +
                       ((colA[i] * 2) ^ ((row & 7) << 4))) = (_Float16)tanh_fast(z);
        }
    }
    BARRIER();                            // B2: h0_new visible; A1 reads done

    // ---- B: acc1 += h0_new @ Wx1 (groups 32..47; stages wrap to 48..50) ----
#pragma unroll
    for (int kc = 0; kc < 16; ++kc){
      STAGE(kc + 35);
      CONSUME(h0nxt, acc1, kc, kc + 32);
    }

    // epilogue1: h1_new = tanh(acc1 + b1) -> h1s (readers sealed by B2/B0)
#pragma unroll
    for (int i = 0; i < 4; ++i)
#pragma unroll
      for (int rg = 0; rg < 4; ++rg){
        int row = rowBase + rg;
        *(_Float16*)(h1s + row * 1024 +
                     ((colA[i] * 2) ^ ((row & 7) << 4))) =
            (_Float16)tanh_fast(acc1[i][rg] + b1c[i]);
      }
    s ^= 1;
  }
#undef STAGE
#undef CONSUME

  asm volatile("s_waitcnt vmcnt(0)" ::: "memory");   // drain wrapped prefetch
  BARRIER();

  // ---- final FC: out[r] = h1[r,:] . Wfc + bfc ----
  {
    int r  = tid >> 5;        // 0..15
    int g2 = tid & 31;
    float p = 0.0f;
#pragma unroll
    for (int k2 = 0; k2 < 16; ++k2){
      int c = g2 + 32 * k2;
      float hv = (float)*(const _Float16*)(h1s + r * 1024 +
                                           ((c * 2) ^ ((r & 7) << 4)));
      p += hv * Wfc[c];
    }
#pragma unroll
    for (int off = 16; off >= 1; off >>= 1) p += __shfl_xor(p, off);
    if (g2 == 0) out[r0 + r] = p + bfc[0];
  }
}

extern "C" void kernel_launch(void* const* d_in, const int* in_sizes, int n_in,
                              void* d_out, int out_size, void* d_ws, size_t ws_size,
                              hipStream_t stream) {
  const float* x   = (const float*)d_in[0];
  const float* Wx0 = (const float*)d_in[1];
  const float* bx0 = (const float*)d_in[2];
  const float* Wh0 = (const float*)d_in[3];
  const float* bh0 = (const float*)d_in[4];
  const float* Wx1 = (const float*)d_in[5];
  const float* bx1 = (const float*)d_in[6];
  const float* Wh1 = (const float*)d_in[7];
  const float* bh1 = (const float*)d_in[8];
  const float* Wfc = (const float*)d_in[9];
  const float* bfc = (const float*)d_in[10];

  _Float16* wsH = (_Float16*)d_ws;
  half8* Wh0f = (half8*)(wsH);
  half8* Wx1f = (half8*)(wsH + 262144);
  half8* Wh1f = (half8*)(wsH + 524288);

  prep_w_45028437131357<<<128, 256, 0, stream>>>(Wh0, Wh0f);
  prep_w_45028437131357<<<128, 256, 0, stream>>>(Wx1, Wx1f);
  prep_w_45028437131357<<<128, 256, 0, stream>>>(Wh1, Wh1f);

  rnn_main_45028437131357<<<128, 512, 0, stream>>>(
      x, Wx0, bx0, bh0, bx1, bh1, Wfc, bfc,
      (const half8*)Wh0f, (const half8*)Wx1f, (const half8*)Wh1f,
      (float*)d_out);
}